// Round 15
// baseline (169.056 us; speedup 1.0000x reference)
//
#include <hip/hip_runtime.h>
#include <hip/hip_bf16.h>
#include <math.h>

#define EDIM 256
#define HDIM 256
#define BDIM 64
#define TDIM 2048
#define NC   64
#define TC   32
#define CPB  4      // chunks per persistent block

typedef __attribute__((ext_vector_type(8)))  short  short8;
typedef __attribute__((ext_vector_type(4)))  float  floatx4;
typedef __attribute__((ext_vector_type(4)))  unsigned int uintx4;

__device__ __forceinline__ unsigned short f2bf(float f) {
    unsigned int u = __float_as_uint(f);
    u += 0x7FFFu + ((u >> 16) & 1u);      // RNE
    return (unsigned short)(u >> 16);
}
__device__ __forceinline__ unsigned int pk2(float a, float b) {
    return (unsigned int)f2bf(a) | ((unsigned int)f2bf(b) << 16);
}
__device__ __forceinline__ float sigm(float x) {
    return __builtin_amdgcn_rcpf(1.f + __expf(-x));
}
__device__ __forceinline__ float tanh_fast(float x) {
    return fmaf(-2.f, __builtin_amdgcn_rcpf(1.f + __expf(2.f * x)), 1.f);
}

// Pack kernel:
//  bx < 256 : Wp fragment-pack (R0 layout).
//  bx >= 256 (mode==1): emb -> bf16 table (halves scattered gather bytes;
//  proven load-bearing in R11).
__global__ __launch_bounds__(256) void qrnn_pack(
    const float* __restrict__ Wq, const float* __restrict__ emb,
    unsigned short* __restrict__ Wp, unsigned short* __restrict__ ebf,
    int mode)
{
    const int bx = blockIdx.x;
    if (bx < 256) {
        const int nt = (bx >> 3) & 7;
        const int hg = bx >> 6;
        const int ks = bx & 7;
        const int t = threadIdx.x;
        const int lane = t >> 2, pj = t & 3;
        const int col = lane & 15, q = lane >> 4;
        const int h = hg * 64 + (nt & 3) * 16 + col;
        const int c = (nt < 4) ? h : (HDIM + h);
        const int k = ks * 32 + q * 8 + pj * 2;
        unsigned int v = pk2(Wq[k * (3 * HDIM) + c], Wq[(k + 1) * (3 * HDIM) + c]);
        *(unsigned int*)(Wp + (size_t)bx * 512 + lane * 8 + pj * 2) = v;
    } else if (mode == 1) {
        size_t i = ((size_t)(bx - 256) * 256 + threadIdx.x) * 8;
        floatx4 a = *(const floatx4*)(emb + i);
        floatx4 b = *(const floatx4*)(emb + i + 4);
        uintx4 o = {pk2(a.x, a.y), pk2(a.z, a.w), pk2(b.x, b.y), pk2(b.z, b.w)};
        *(uintx4*)(ebf + i) = o;
    }
}

// Main: R8 body with WAVE SPECIALIZATION over (batch-pair x nt-pair).
// 512 blocks x 512 thr, 2 blk/CU.  Wave w = (bp = w>>1, nh = w&1):
// 2 batches (4 mt) x 4 nt columns -- z-cols {2nh,2nh+1} paired with their
// f-cols {4+2nh,4+2nh+1} so the z/f gate epilogue stays wave-local.
// Per ks-step: 4 ds_read_b128 instead of 8 -> block LDS-read traffic HALVES
// (the largest component of the 51.5us: 4096 b128/CU x ~12cy ~= 20us).
// Per-wave MFMA count unchanged (4mt x 4s = 16/ks).  A-loads double per
// wave (scattered-request axis exonerated in R9), issued as two 16-load
// half-bursts so peak A-register pressure equals R8's.  Store: lanes with
// (q>>1)==nh write h = lane (full non-overlapping coverage).  Numerics
// bit-identical.  Tripwires: VGPR>128 or WRITE_SIZE>10MB => spill.
template<int MODE>
__global__ __launch_bounds__(512, 2) void qrnn_mfma(
    const int* __restrict__ X, const float* __restrict__ emb,
    const unsigned short* __restrict__ ebf, const unsigned short* __restrict__ Wp,
    const float* __restrict__ bq, float* __restrict__ wsA, float* __restrict__ wsB)
{
    __shared__ __align__(16) short Bsh[32768];   // 64 KB: [nt*8+ks][64 lanes][8]

    const int tid = threadIdx.x;
    const int cg = blockIdx.x, bg = blockIdx.y, hg = blockIdx.z;
    const int lane = tid & 63, w = tid >> 6;     // w in [0,8)
    const int col = lane & 15, q = lane >> 4;
    const int bp = w >> 1, nh = w & 1;           // batch-pair, nt-half

    // Stage B slice (64 KB, all ks) once: 64 rows / 8 waves = 8 each.
    const unsigned short* wpb = Wp + (size_t)hg * 32768;
#pragma unroll
    for (int i = 0; i < 8; ++i) {
        const int ch = w * 8 + i;           // wave-uniform
        __builtin_amdgcn_global_load_lds(
            (const __attribute__((address_space(1))) unsigned int*)(wpb + ch * 512 + lane * 8),
            (__attribute__((address_space(3))) unsigned int*)(Bsh + ch * 512),
            16, 0, 0);
    }

    const int b0 = bg * 8 + bp * 2;         // two batches per wave
    int xid[CPB][4];
#pragma unroll
    for (int c = 0; c < CPB; ++c)
#pragma unroll
        for (int mt = 0; mt < 4; ++mt)
            xid[c][mt] = X[(b0 + (mt >> 1)) * TDIM + (cg * CPB + c) * TC + (mt & 1) * 16 + col];

    const int hbase = hg * 64;
    float bz[2], bfv[2];
#pragma unroll
    for (int ntl = 0; ntl < 2; ++ntl) {
        bz[ntl]  = bq[hbase + (nh * 2 + ntl) * 16 + col];
        bfv[ntl] = bq[HDIM + hbase + (nh * 2 + ntl) * 16 + col];
    }

    // Bsh row bases for this wave's 4 nt columns (z0, z1, f0, f1).
    const int rz0 = (nh * 2) * 8, rz1 = (nh * 2 + 1) * 8;
    const int rf0 = (4 + nh * 2) * 8, rf1 = (5 + nh * 2) * 8;

    floatx4 acc[4][4];   // [mt][s]: s = 0,1 -> z ntl 0,1 ; s = 2,3 -> f ntl 0,1
#pragma unroll
    for (int mt = 0; mt < 4; ++mt)
#pragma unroll
        for (int s = 0; s < 4; ++s) acc[mt][s] = (floatx4){0.f, 0.f, 0.f, 0.f};

    __syncthreads();   // Bsh staging complete (drains vmem)

#pragma unroll
    for (int c = 0; c < CPB; ++c) {
#pragma unroll
        for (int half = 0; half < 2; ++half) {
            // ---- 16-load half-burst (static indices), ks = half*4 + k4. ----
            short8 abuf[4][4];
#pragma unroll
            for (int k4 = 0; k4 < 4; ++k4)
#pragma unroll
                for (int mt = 0; mt < 4; ++mt) {
                    const int ks = half * 4 + k4;
                    if constexpr (MODE == 1) {
                        abuf[k4][mt] = *(const short8*)(ebf + (size_t)xid[c][mt] * EDIM + q * 8 + ks * 32);
                    } else {
                        const float* ap = emb + (size_t)xid[c][mt] * EDIM + q * 8 + ks * 32;
                        floatx4 f0 = *(const floatx4*)ap;
                        floatx4 f1 = *(const floatx4*)(ap + 4);
                        uintx4 p = {pk2(f0.x, f0.y), pk2(f0.z, f0.w),
                                    pk2(f1.x, f1.y), pk2(f1.z, f1.w)};
                        abuf[k4][mt] = *(short8*)&p;
                    }
                }

#pragma unroll
            for (int k4 = 0; k4 < 4; ++k4) {
                const int ks = half * 4 + k4;
                short8 bz0 = *(const short8*)(Bsh + (rz0 + ks) * 512 + lane * 8);
                short8 bz1 = *(const short8*)(Bsh + (rz1 + ks) * 512 + lane * 8);
                short8 bf0 = *(const short8*)(Bsh + (rf0 + ks) * 512 + lane * 8);
                short8 bf1 = *(const short8*)(Bsh + (rf1 + ks) * 512 + lane * 8);
#pragma unroll
                for (int mt = 0; mt < 4; ++mt) {
                    acc[mt][0] = __builtin_amdgcn_mfma_f32_16x16x32_bf16(abuf[k4][mt], bz0, acc[mt][0], 0, 0, 0);
                    acc[mt][1] = __builtin_amdgcn_mfma_f32_16x16x32_bf16(abuf[k4][mt], bz1, acc[mt][1], 0, 0, 0);
                    acc[mt][2] = __builtin_amdgcn_mfma_f32_16x16x32_bf16(abuf[k4][mt], bf0, acc[mt][2], 0, 0, 0);
                    acc[mt][3] = __builtin_amdgcn_mfma_f32_16x16x32_bf16(abuf[k4][mt], bf1, acc[mt][3], 0, 0, 0);
                }
            }
        }

        // Epilogue for chunk cc: t = q*4 + j (+16*(mt&1)), batch b0+(mt>>1).
        const int cc = cg * CPB + c;
        float Af0[2], Bf0[2], Af1[2], Bf1[2];
#pragma unroll
        for (int ntl = 0; ntl < 2; ++ntl) {
            float Aseg[4], Bseg[4];
#pragma unroll
            for (int mt = 0; mt < 4; ++mt) {
                float Ac = 1.f, Bc = 0.f;
#pragma unroll
                for (int j = 0; j < 4; ++j) {
                    float z = tanh_fast(acc[mt][ntl][j] + bz[ntl]);
                    float f = sigm(acc[mt][ntl + 2][j] + bfv[ntl]);
                    Ac = f * Ac;
                    Bc = fmaf(f, Bc, (1.f - f) * z);
                }
                Aseg[mt] = Ac; Bseg[mt] = Bc;
            }
#pragma unroll
            for (int st = 0; st < 2; ++st) {
                const int msk = 16 << st;
                const bool self_earlier = ((q >> st) & 1) == 0;
#pragma unroll
                for (int mt = 0; mt < 4; ++mt) {
                    float Ap = __shfl_xor(Aseg[mt], msk, 64);
                    float Bp = __shfl_xor(Bseg[mt], msk, 64);
                    Bseg[mt] = self_earlier ? fmaf(Ap, Bseg[mt], Bp)
                                            : fmaf(Aseg[mt], Bp, Bseg[mt]);
                    Aseg[mt] = Aseg[mt] * Ap;
                }
            }
            Af0[ntl] = Aseg[0] * Aseg[1];                 // batch b0
            Bf0[ntl] = fmaf(Aseg[1], Bseg[0], Bseg[1]);
            Af1[ntl] = Aseg[2] * Aseg[3];                 // batch b0+1
            Bf1[ntl] = fmaf(Aseg[3], Bseg[2], Bseg[3]);
        }

        // Store: lanes with (q>>1)==nh own h = lane (= q*16+col); ntl = q&1.
        if ((q >> 1) == nh) {
            const int ntl = q & 1;
            float As0 = ntl ? Af0[1] : Af0[0];
            float Bs0 = ntl ? Bf0[1] : Bf0[0];
            float As1 = ntl ? Af1[1] : Af1[0];
            float Bs1 = ntl ? Bf1[1] : Bf1[0];
            const size_t r0 = ((size_t)cc * BDIM + b0) * HDIM + hbase + lane;
            wsA[r0] = As0;          wsB[r0] = Bs0;
            wsA[r0 + HDIM] = As1;   wsB[r0 + HDIM] = Bs1;
        }

#pragma unroll
        for (int mt = 0; mt < 4; ++mt)
#pragma unroll
            for (int s = 0; s < 4; ++s) acc[mt][s] = (floatx4){0.f, 0.f, 0.f, 0.f};
    }
}

// Combine chunk (A,B) pairs + o-gate at t=T-1 + output dot.
__global__ __launch_bounds__(256) void qrnn_combine(
    const float* __restrict__ wsA, const float* __restrict__ wsB,
    const float* __restrict__ c0, const int* __restrict__ X,
    const float* __restrict__ emb, const float* __restrict__ Wq,
    const float* __restrict__ bq, const float* __restrict__ Wout,
    const float* __restrict__ bout, float* __restrict__ out)
{
    const int b = blockIdx.x;
    const int h = threadIdx.x;

    float c = c0[b * HDIM + h];
    for (int c8 = 0; c8 < NC; c8 += 8) {
        float a[8], bb[8];
#pragma unroll
        for (int i = 0; i < 8; ++i) {
            size_t base = ((size_t)(c8 + i) * BDIM + b) * HDIM + h;
            a[i]  = wsA[base];
            bb[i] = wsB[base];
        }
#pragma unroll
        for (int i = 0; i < 8; ++i) c = fmaf(a[i], c, bb[i]);
    }

    __shared__ float xs[EDIM];
    int idx = X[b * TDIM + (TDIM - 1)];
    xs[h] = emb[(size_t)idx * EDIM + h];
    __syncthreads();

    float acc = 0.f;
#pragma unroll 16
    for (int e = 0; e < EDIM; ++e)
        acc = fmaf(xs[e], Wq[e * (3 * HDIM) + 2 * HDIM + h], acc);

    float o  = 1.f / (1.f + expf(-(acc + bq[2 * HDIM + h])));
    float hn = o * c;

    __shared__ float red[HDIM];
    red[h] = hn * Wout[h];
    __syncthreads();
    for (int s = HDIM / 2; s > 0; s >>= 1) {
        if (h < s) red[h] += red[h + s];
        __syncthreads();
    }
    if (h == 0) out[b] = red[0] + bout[0];
}

extern "C" void kernel_launch(void* const* d_in, const int* in_sizes, int n_in,
                              void* d_out, int out_size, void* d_ws, size_t ws_size,
                              hipStream_t stream) {
    const int*   X    = (const int*)d_in[0];
    const float* emb  = (const float*)d_in[1];
    const float* Wq   = (const float*)d_in[2];
    const float* bq   = (const float*)d_in[3];
    const float* c0   = (const float*)d_in[4];
    const float* Wout = (const float*)d_in[5];
    const float* bout = (const float*)d_in[6];
    float* out = (float*)d_out;

    float* wsA = (float*)d_ws;                        // [NC][B][H]
    float* wsB = wsA + (size_t)NC * BDIM * HDIM;      // [NC][B][H]
    unsigned short* Wp  = (unsigned short*)(wsB + (size_t)NC * BDIM * HDIM);  // 256 KB
    unsigned short* ebf = Wp + (size_t)256 * 512;     // 16.4 MB bf16 emb table

    const size_t wsAB = (size_t)2 * NC * BDIM * HDIM * 4;
    const size_t wpsz = (size_t)256 * 512 * 2;
    const size_t need1 = wsAB + wpsz + (size_t)32000 * EDIM * 2;   // ~25.0 MB
    const int mode = (ws_size >= need1) ? 1 : 0;

    const int gather_blocks = (mode == 1) ? (32000 * EDIM / 8) / 256 : 0;  // 4000
    qrnn_pack<<<256 + gather_blocks, 256, 0, stream>>>(Wq, emb, Wp, ebf, mode);

    dim3 g(NC / CPB, BDIM / 8, HDIM / 64);   // 16 x 8 x 4 = 512 blocks of 512 thr (2/CU)
    if (mode == 1) qrnn_mfma<1><<<g, 512, 0, stream>>>(X, emb, ebf, Wp, bq, wsA, wsB);
    else           qrnn_mfma<0><<<g, 512, 0, stream>>>(X, emb, ebf, Wp, bq, wsA, wsB);

    qrnn_combine<<<BDIM, 256, 0, stream>>>(wsA, wsB, c0, X, emb, Wq, bq, Wout, bout, out);
}